// Round 10
// baseline (9285.116 us; speedup 1.0000x reference)
//
#include <hip/hip_runtime.h>
#include <cmath>

#define REGP 0.1f
#define NIT 200
#define K2 14.4269504089f        // log2(e)/reg
#define CREF 28.5f               // centering constant for f
#define CLO  23.5f               // u8 quantization lower bound
#define QSV  (17.0f/255.0f)      // quant step
#define QIV  15.0f               // 1/QSV
#define S2V  (QSV*K2)

#define NBLK 256                 // k_sink grid (1 block/CU, LDS-bound)
#define NTHR 512                 // 8 waves/block
#define NGRP 8
#define GSZ  (NBLK/NGRP)         // 32 arrivals per group counter

// k_sink dynamic LDS layout (bytes)
#define SM_C    0                // u8 C rows: 16 x 8192 = 131072
#define SM_VKH  131072           // staged vector half: 4096 f32 = 16384
#define SM_SRED 147456           // reduce scratch: 32 f32 = 128
#define SM_SIZE 147584

typedef float  vf4  __attribute__((ext_vector_type(4)));
typedef short  vbf8 __attribute__((ext_vector_type(8)));
typedef unsigned short vu8 __attribute__((ext_vector_type(8)));

#if defined(__has_builtin) && __has_builtin(__builtin_amdgcn_exp2f)
#define EXP2F(x) __builtin_amdgcn_exp2f(x)
#else
#define EXP2F(x) exp2f(x)
#endif

static __device__ __forceinline__ unsigned short f2bf(float x) {
    unsigned int u = __float_as_uint(x);
    return (unsigned short)((u + 0x7FFFu + ((u >> 16) & 1u)) >> 16);
}

static __device__ __forceinline__ float wave_red_sum(float v) {
    #pragma unroll
    for (int o = 32; o > 0; o >>= 1) v += __shfl_xor(v, o, 64);
    return v;
}

// 16 u8 cost values vs 16 vk values; 4 independent accumulators
static __device__ __forceinline__ void acc16(uint4 c, const vf4* gv, vf4& sacc) {
    #pragma unroll
    for (int d = 0; d < 4; ++d) {
        unsigned x = d == 0 ? c.x : d == 1 ? c.y : d == 2 ? c.z : c.w;
        vf4 g = gv[d];
        sacc[0] += EXP2F(fmaf((float)(x & 0xffu),         -S2V, g[0]));
        sacc[1] += EXP2F(fmaf((float)((x >> 8) & 0xffu),  -S2V, g[1]));
        sacc[2] += EXP2F(fmaf((float)((x >> 16) & 0xffu), -S2V, g[2]));
        sacc[3] += EXP2F(fmaf((float)(x >> 24),           -S2V, g[3]));
    }
}

// ---------------- hierarchical reset-free grid barrier (R7-validated) ----------------

static __device__ __forceinline__ void gbar(unsigned* bar, unsigned bi, int blk) {
    __syncthreads();
    if (threadIdx.x == 0) {
        int g = blk & (NGRP - 1);
        unsigned* cnt = bar + 32 * (1 + g);
        unsigned* gen = bar + 32 * (9 + g);
        unsigned old = __hip_atomic_fetch_add(cnt, 1u, __ATOMIC_RELAXED, __HIP_MEMORY_SCOPE_AGENT);
        if (old == bi * GSZ - 1u) {                 // last of my group
            unsigned r = __hip_atomic_fetch_add(bar, 1u, __ATOMIC_RELAXED, __HIP_MEMORY_SCOPE_AGENT);
            if (r == bi * NGRP - 1u) {              // last group globally: release all
                #pragma unroll
                for (int k = 0; k < NGRP; ++k)
                    __hip_atomic_store(bar + 32 * (9 + k), bi, __ATOMIC_RELAXED, __HIP_MEMORY_SCOPE_AGENT);
            } else {
                while (__hip_atomic_load(gen, __ATOMIC_RELAXED, __HIP_MEMORY_SCOPE_AGENT) < bi)
                    __builtin_amdgcn_s_sleep(4);
            }
        } else {
            while (__hip_atomic_load(gen, __ATOMIC_RELAXED, __HIP_MEMORY_SCOPE_AGENT) < bi)
                __builtin_amdgcn_s_sleep(4);
        }
    }
    __syncthreads();
}

// ---------------- stage 4096 f32 (sc-bypass) into LDS, granule-XOR-swizzled ----------------
// logical 16B-granule G stored at physical G ^ ((G>>3)&7); 2 granules/thread.

static __device__ __forceinline__ void stage_vec(const float* src, float* lds) {
    int tid = threadIdx.x;
    const unsigned long long* p = (const unsigned long long*)src;
    #pragma unroll
    for (int i = 0; i < 2; ++i) {
        int gr = i * NTHR + tid;
        unsigned long long lo = __hip_atomic_load(&p[(size_t)gr * 2],
                                    __ATOMIC_RELAXED, __HIP_MEMORY_SCOPE_AGENT);
        unsigned long long hi = __hip_atomic_load(&p[(size_t)gr * 2 + 1],
                                    __ATOMIC_RELAXED, __HIP_MEMORY_SCOPE_AGENT);
        int pg = gr ^ ((gr >> 3) & 7);
        *(unsigned long long*)(lds + pg * 4)     = lo;
        *(unsigned long long*)(lds + pg * 4 + 2) = hi;
    }
}

// ---------------- prep kernels ----------------

__global__ void k_init(float* gk, float* scalars, unsigned* bar, int M) {
    int i = blockIdx.x * blockDim.x + threadIdx.x;
    if (i < M) gk[i] = 5.0f * K2;        // g=0: gk=(0+CREF-CLO)*K2
    if (i < 8) scalars[i] = 0.f;
    if (i < 1024) bar[i] = 0u;
}

__global__ void k_convnorm(const float* __restrict__ X, unsigned short* __restrict__ Xb,
                           float* __restrict__ xx, int D) {
    int row = blockIdx.x, lane = threadIdx.x;
    const float* p = X + (size_t)row * D;
    unsigned short* q = Xb + (size_t)row * D;
    float sq = 0.f;
    for (int base = lane * 8; base < D; base += 512) {
        vf4 a = *(const vf4*)(p + base);
        vf4 b = *(const vf4*)(p + base + 4);
        vu8 o;
        #pragma unroll
        for (int e = 0; e < 4; ++e) {
            o[e]     = f2bf(a[e]);
            o[4 + e] = f2bf(b[e]);
            sq += a[e] * a[e] + b[e] * b[e];
        }
        *(vu8*)(q + base) = o;
    }
    sq = wave_red_sum(sq);
    if (lane == 0) xx[row] = sq;
}

__global__ void k_sumtgt(const float* __restrict__ t, float* scalars, int M) {
    __shared__ float red[4];
    float s = 0.f;
    for (int i = threadIdx.x; i < M; i += 256) s += t[i];
    s = wave_red_sum(s);
    if ((threadIdx.x & 63) == 0) red[threadIdx.x >> 6] = s;
    __syncthreads();
    if (threadIdx.x == 0) scalars[3] = logf(red[0] + red[1] + red[2] + red[3]);
}

__global__ void k_rlb(const float* __restrict__ tgt, const float* __restrict__ scalars,
                      float* __restrict__ rlb, int M) {
    int j = blockIdx.x * 256 + threadIdx.x;
    if (j < M) rlb[j] = REGP * (logf(tgt[j]) - scalars[3]);
}

// ---------------- cost matrix: OUT[i][j] = quant_u8(sqrt(an[i]+bn[j]-2 A_i.B_j)) ----------------

__global__ __launch_bounds__(256, 2)
void k_gemm(const unsigned short* __restrict__ A, const unsigned short* __restrict__ B,
            const float* __restrict__ an, const float* __restrict__ bn,
            unsigned char* __restrict__ OUT, int ldo, int D) {
    int m0 = blockIdx.y * 128, n0 = blockIdx.x * 128;
    int wave = threadIdx.x >> 6, lane = threadIdx.x & 63;
    int lr = lane & 15, lk = (lane >> 4) * 8;
    const unsigned short* ax = A + (size_t)(m0 + wave * 32 + lr) * D + lk;
    const unsigned short* bx = B + (size_t)(n0 + lr) * D + lk;
    vf4 acc[2][8];
    #pragma unroll
    for (int r = 0; r < 2; ++r)
        #pragma unroll
        for (int c = 0; c < 8; ++c) acc[r][c] = (vf4){0.f, 0.f, 0.f, 0.f};

    for (int k = 0; k < D; k += 32) {
        vbf8 a0 = *(const vbf8*)(ax + k);
        vbf8 a1 = *(const vbf8*)(ax + 16 * D + k);
        #pragma unroll
        for (int c = 0; c < 8; ++c) {
            vbf8 b = *(const vbf8*)(bx + (size_t)c * 16 * D + k);
            acc[0][c] = __builtin_amdgcn_mfma_f32_16x16x32_bf16(a0, b, acc[0][c], 0, 0, 0);
            acc[1][c] = __builtin_amdgcn_mfma_f32_16x16x32_bf16(a1, b, acc[1][c], 0, 0, 0);
        }
    }
    int rbase = m0 + wave * 32 + (lane >> 4) * 4;
    #pragma unroll
    for (int r = 0; r < 2; ++r) {
        #pragma unroll
        for (int q = 0; q < 4; ++q) {
            int i = rbase + r * 16 + q;
            float xi = an[i];
            #pragma unroll
            for (int c = 0; c < 8; ++c) {
                int j = n0 + c * 16 + lr;
                float sq = xi + bn[j] - 2.f * acc[r][c][q];
                float cv = sqrtf(fmaxf(sq, 1e-12f));
                float qv = fminf(fmaxf((cv - CLO) * QIV, 0.f), 255.f);
                OUT[(size_t)i * ldo + j] = (unsigned char)(qv + 0.5f);
            }
        }
    }
}

// ---------------- persistent sinkhorn: C in LDS (f-pass), CT in L2 (g-pass) ----------------
// 256 blocks x 512 thr, 1 block/CU, 144.2 KB LDS. Block owns 16 C-rows (LDS)
// and 32 CT-rows (128 KB -> stable per-XCD L2 working set: 32 blk x 128 KB = 4 MB).
// Per iter: f-pass (LDS C, gk staged per half) -> f, fk[16] sc; gbar;
//           g-pass (L2 CT, fk staged once)     -> gk[32] sc;    gbar.

__global__ __launch_bounds__(NTHR, 1)
void k_sink(const unsigned char* __restrict__ C, const unsigned char* __restrict__ CT,
            float* __restrict__ f, float* fk, float* gk,
            const float* __restrict__ rlb, float rla,
            unsigned* bar, int N, int M) {
    extern __shared__ char smem[];
    unsigned char* cl = (unsigned char*)(smem + SM_C);
    float* vkh  = (float*)(smem + SM_VKH);
    float* sred = (float*)(smem + SM_SRED);
    int blk = blockIdx.x, tid = threadIdx.x;
    int w = tid >> 6, l = tid & 63;
    int xr = (l >> 1) & 7;

    // one-time: load my 16 rows of C into LDS (128 KB)
    {
        const unsigned char* src = C + (size_t)blk * 16 * M;
        #pragma unroll
        for (int r = 0; r < 16; ++r)
            *(uint4*)(cl + r * 8192 + tid * 16) =
                *(const uint4*)(src + (size_t)r * M + tid * 16);
    }

    unsigned bi = 0;
    for (int it = 0; it < NIT; ++it) {
        // ---------- f-pass: 2 rows/wave from LDS C; gk staged in halves ----------
        vf4 sA = (vf4){0.f,0.f,0.f,0.f}, sB = (vf4){0.f,0.f,0.f,0.f};
        const unsigned char* r0p = cl + (w * 2) * 8192;
        #pragma unroll
        for (int H = 0; H < 2; ++H) {
            __syncthreads();                  // vkh safe to overwrite
            stage_vec(gk + H * 4096, vkh);
            __syncthreads();
            #pragma unroll
            for (int ch = 0; ch < 4; ++ch) {
                uint4 a = *(const uint4*)(r0p + H * 4096 + ch * 1024 + l * 16);
                uint4 b = *(const uint4*)(r0p + 8192 + H * 4096 + ch * 1024 + l * 16);
                int G0 = ch * 256 + l * 4;
                vf4 gv[4];
                #pragma unroll
                for (int q = 0; q < 4; ++q)
                    gv[q] = *(const vf4*)(vkh + (size_t)((G0 + q) ^ xr) * 4);
                acc16(a, gv, sA);
                acc16(b, gv, sB);
            }
        }
        float s0 = wave_red_sum(sA[0] + sA[1] + sA[2] + sA[3]);
        float s1 = wave_red_sum(sB[0] + sB[1] + sB[2] + sB[3]);
        if (l == 0) { sred[w * 2] = s0; sred[w * 2 + 1] = s1; }
        __syncthreads();
        if (tid < 16) {
            float val = rla + CREF - log2f(sred[tid]) * (1.0f / K2);
            f[blk * 16 + tid] = val;          // plain; flushed at kernel end for k_ot
            __hip_atomic_store(&fk[blk * 16 + tid], (val - CLO) * K2,
                               __ATOMIC_RELAXED, __HIP_MEMORY_SCOPE_AGENT);
        }
        gbar(bar, ++bi, blk);
        // ---------- g-pass: 4 CT rows/wave from L2; fk staged once ----------
        stage_vec(fk, vkh);
        __syncthreads();
        #pragma unroll
        for (int pr = 0; pr < 2; ++pr) {
            int rA = blk * 32 + w * 4 + pr * 2;
            const unsigned char* cpA = CT + (size_t)rA * N + l * 16;
            const unsigned char* cpB = cpA + N;
            vf4 tA = (vf4){0.f,0.f,0.f,0.f}, tB = (vf4){0.f,0.f,0.f,0.f};
            #pragma unroll
            for (int ch = 0; ch < 4; ++ch) {
                uint4 a = *(const uint4*)(cpA + ch * 1024);
                uint4 b = *(const uint4*)(cpB + ch * 1024);
                int G0 = ch * 256 + l * 4;
                vf4 gv[4];
                #pragma unroll
                for (int q = 0; q < 4; ++q)
                    gv[q] = *(const vf4*)(vkh + (size_t)((G0 + q) ^ xr) * 4);
                acc16(a, gv, tA);
                acc16(b, gv, tB);
            }
            float t0 = wave_red_sum(tA[0] + tA[1] + tA[2] + tA[3]);
            float t1 = wave_red_sum(tB[0] + tB[1] + tB[2] + tB[3]);
            if (l == 0) { sred[w * 4 + pr * 2] = t0; sred[w * 4 + pr * 2 + 1] = t1; }
        }
        __syncthreads();
        if (tid < 32) {
            int col = blk * 32 + tid;
            float kv = (rlb[col] - log2f(sred[tid]) * (1.0f / K2) + (CREF - CLO)) * K2;
            __hip_atomic_store(&gk[col], kv, __ATOMIC_RELAXED, __HIP_MEMORY_SCOPE_AGENT);
        }
        gbar(bar, ++bi, blk);
    }
}

// ---------------- epilogue: sum P*C' ----------------

__global__ __launch_bounds__(256)
void k_ot(const unsigned char* __restrict__ C, const float* __restrict__ f,
          const float* __restrict__ gk, float* __restrict__ scalars, int M) {
    int row = blockIdx.x * 4 + (threadIdx.x >> 6);
    int lane = threadIdx.x & 63;
    const unsigned char* cp = C + (size_t)row * M;
    float fk2 = (f[row] - CREF) * K2;
    float acc = 0.f;
    for (int base = lane * 16; base < M; base += 1024) {
        uint4 cw = *(const uint4*)(cp + base);
        #pragma unroll
        for (int d = 0; d < 4; ++d) {
            unsigned x = d == 0 ? cw.x : d == 1 ? cw.y : d == 2 ? cw.z : cw.w;
            vf4 g = *(const vf4*)(gk + base + d * 4);
            #pragma unroll
            for (int e = 0; e < 4; ++e) {
                float uf = (float)((x >> (8 * e)) & 0xffu);
                float t = fmaf(uf, -S2V, fk2 + g[e]);
                float cval = fmaf(uf, QSV, CLO);
                acc = fmaf(EXP2F(t), cval, acc);
            }
        }
    }
    acc = wave_red_sum(acc);
    if (lane == 0) atomicAdd(&scalars[0], acc);
}

__global__ void k_dist(const float* __restrict__ X, const float* __restrict__ Y,
                       const int* __restrict__ aligned, float* __restrict__ scalars, int D) {
    int i = blockIdx.x, lane = threadIdx.x;
    int a = aligned[i];
    if (a == -1) return;
    const float* xp = X + (size_t)i * D;
    const float* yp = Y + (size_t)a * D;
    float sq = 0.f;
    for (int base = lane * 8; base < D; base += 512) {
        vf4 x0 = *(const vf4*)(xp + base), x1 = *(const vf4*)(xp + base + 4);
        vf4 y0 = *(const vf4*)(yp + base), y1 = *(const vf4*)(yp + base + 4);
        #pragma unroll
        for (int e = 0; e < 4; ++e) {
            float d0 = x0[e] - y0[e], d1 = x1[e] - y1[e];
            sq += d0 * d0 + d1 * d1;
        }
    }
    sq = wave_red_sum(sq);
    if (lane == 0) { atomicAdd(&scalars[1], sq); atomicAdd(&scalars[2], 1.0f); }
}

__global__ void k_final(float* out, const float* __restrict__ scalars, int D) {
    float cnt = scalars[2];
    float dist = cnt > 0.f ? scalars[1] / (cnt * (float)D) : 0.f;
    out[0] = scalars[0] + dist;
}

// ---------------- host ----------------

extern "C" void kernel_launch(void* const* d_in, const int* in_sizes, int n_in,
                              void* d_out, int out_size, void* d_ws, size_t ws_size,
                              hipStream_t stream) {
    const float* X = (const float*)d_in[0];
    const float* Y = (const float*)d_in[1];
    const int* aligned = (const int*)d_in[2];
    const float* tgt = (const float*)d_in[3];
    int N = in_sizes[2];              // 4096
    int M = in_sizes[3];              // 8192
    int D = in_sizes[0] / N;          // 512
    float* out = (float*)d_out;

    char* w = (char*)d_ws;
    size_t off = 0;
    auto alloc = [&](size_t bytes) -> void* {
        void* p = w + off;
        off += (bytes + 255) & ~(size_t)255;
        return p;
    };
    unsigned short* Xb = (unsigned short*)alloc((size_t)N * D * 2);
    unsigned short* Yb = (unsigned short*)alloc((size_t)M * D * 2);
    unsigned char* C  = (unsigned char*)alloc((size_t)N * M);
    unsigned char* CT = (unsigned char*)alloc((size_t)N * M);
    float* xx  = (float*)alloc((size_t)N * 4);
    float* yy  = (float*)alloc((size_t)M * 4);
    float* f   = (float*)alloc((size_t)N * 4);
    float* fk  = (float*)alloc((size_t)N * 4);
    float* gk  = (float*)alloc((size_t)M * 4);
    float* rlb = (float*)alloc((size_t)M * 4);
    float* scalars = (float*)alloc(64);
    unsigned* bar = (unsigned*)alloc(4096);
    if (off > ws_size) return;

    float rla = -REGP * logf((float)N);

    // opt-in to >64KB dynamic LDS for k_sink (idempotent, non-stream, graph-safe)
    hipFuncSetAttribute((const void*)k_sink,
                        hipFuncAttributeMaxDynamicSharedMemorySize, SM_SIZE);

    k_init<<<dim3((M + 255) / 256), 256, 0, stream>>>(gk, scalars, bar, M);
    k_convnorm<<<dim3(N), 64, 0, stream>>>(X, Xb, xx, D);
    k_convnorm<<<dim3(M), 64, 0, stream>>>(Y, Yb, yy, D);
    k_sumtgt<<<1, 256, 0, stream>>>(tgt, scalars, M);
    k_rlb<<<dim3((M + 255) / 256), 256, 0, stream>>>(tgt, scalars, rlb, M);
    k_gemm<<<dim3(M / 128, N / 128), 256, 0, stream>>>(Xb, Yb, xx, yy, C,  M, D);
    k_gemm<<<dim3(N / 128, M / 128), 256, 0, stream>>>(Yb, Xb, yy, xx, CT, N, D);

    // persistent sinkhorn: one launch, LDS-resident C + L2-resident CT
    k_sink<<<dim3(NBLK), NTHR, SM_SIZE, stream>>>(C, CT, f, fk, gk, rlb, rla, bar, N, M);

    k_ot<<<dim3(N / 4), 256, 0, stream>>>(C, f, gk, scalars, M);
    k_dist<<<dim3(N), 64, 0, stream>>>(X, Y, aligned, scalars, D);
    k_final<<<1, 1, 0, stream>>>(out, scalars, D);
}